// Round 3
// baseline (742.940 us; speedup 1.0000x reference)
//
#include <hip/hip_runtime.h>
#include <hip/hip_bf16.h>

// Problem constants
#define B_   8
#define N_   1024
#define M_   128
#define C_   1024
#define H_   16
#define D_   64
#define MLP_ 4096

typedef __bf16 bf16;
typedef __bf16 bf16x8 __attribute__((ext_vector_type(8)));
typedef __bf16 bf16x4 __attribute__((ext_vector_type(4)));
typedef float  f32x4  __attribute__((ext_vector_type(4)));

__device__ __forceinline__ f32x4 mfma16(bf16x8 a, bf16x8 b, f32x4 c) {
    return __builtin_amdgcn_mfma_f32_16x16x32_bf16(a, b, c, 0, 0, 0);
}

// async global->LDS, 16 B per lane (LDS dest wave-uniform base + lane*16)
__device__ __forceinline__ void gload16(const bf16* g, bf16* l) {
    __builtin_amdgcn_global_load_lds(
        (const __attribute__((address_space(1))) void*)g,
        (__attribute__((address_space(3))) void*)l, 16, 0, 0);
}

// ---------------------------------------------------------------------------
// Weight transpose + fp32->bf16:  W (K x Nc) fp32  ->  Wt (Nc x K) bf16
// ---------------------------------------------------------------------------
__global__ __launch_bounds__(256) void transpose_k(const float* __restrict__ W,
                                                   bf16* __restrict__ Wt,
                                                   int K, int Nc) {
    __shared__ float tile[32][33];
    const int x  = threadIdx.x & 31;
    const int y0 = threadIdx.x >> 5;
    const size_t n0 = (size_t)blockIdx.x * 32;
    const size_t k0 = (size_t)blockIdx.y * 32;
#pragma unroll
    for (int i = 0; i < 4; i++)
        tile[y0 + i * 8][x] = W[(k0 + y0 + i * 8) * Nc + n0 + x];
    __syncthreads();
#pragma unroll
    for (int i = 0; i < 4; i++)
        Wt[(n0 + y0 + i * 8) * K + k0 + x] = (bf16)tile[x][y0 + i * 8];
}

// bf16 V transpose: in rows (b*Mk + m), cols coff+hd -> outT[(b*1024+hd)*Mk + m]
__global__ __launch_bounds__(256) void vtrans_k(const bf16* __restrict__ in, int instride,
                                                int coff, int Mk, bf16* __restrict__ outT) {
    __shared__ bf16 t[32][33];
    const int tx = threadIdx.x & 31;
    const int ty0 = threadIdx.x >> 5;
    const int m0  = blockIdx.x * 32;
    const int hd0 = blockIdx.y * 32;
    const int b   = blockIdx.z;
#pragma unroll
    for (int i = 0; i < 4; i++)
        t[ty0 + i * 8][tx] = in[((size_t)(b * Mk + m0 + ty0 + i * 8)) * instride + coff + hd0 + tx];
    __syncthreads();
#pragma unroll
    for (int i = 0; i < 4; i++)
        outT[((size_t)(b * 1024 + hd0 + ty0 + i * 8)) * Mk + m0 + tx] = t[tx][ty0 + i * 8];
}

// fp32 -> bf16 elementwise (n4 = count/4)
__global__ __launch_bounds__(256) void cvt_bf16_k(const float* __restrict__ in,
                                                  bf16* __restrict__ out, int n4) {
    int i = blockIdx.x * 256 + threadIdx.x;
    if (i < n4) {
        float4 v = ((const float4*)in)[i];
        bf16x4 o;
        o[0] = (bf16)v.x; o[1] = (bf16)v.y; o[2] = (bf16)v.z; o[3] = (bf16)v.w;
        ((bf16x4*)out)[i] = o;
    }
}

// ---------------------------------------------------------------------------
// ada = silu(c_dino) @ W_ada + b_ada   (8 x 6144) fp32, split-K with atomics.
// ---------------------------------------------------------------------------
__global__ __launch_bounds__(256) void ada_init_k(const float* __restrict__ bias,
                                                  float* __restrict__ ada) {
    int i = blockIdx.x * 256 + threadIdx.x;
    ada[i] = bias[i % 6144];
}

__global__ __launch_bounds__(256) void ada_k(const float* __restrict__ cdino,
                                             const float* __restrict__ W,
                                             float* __restrict__ ada) {
    __shared__ float sc[8][32];
    const int tid = threadIdx.x;
    const int k0  = blockIdx.y * 32;
    {
        float c = cdino[(tid >> 5) * 1024 + k0 + (tid & 31)];
        sc[tid >> 5][tid & 31] = c / (1.f + __expf(-c));
    }
    __syncthreads();
    const int col = blockIdx.x * 256 + tid;
    float acc[8];
#pragma unroll
    for (int b = 0; b < 8; b++) acc[b] = 0.f;
    for (int kk = 0; kk < 32; kk++) {
        float w = W[(size_t)(k0 + kk) * 6144 + col];
#pragma unroll
        for (int b = 0; b < 8; b++) acc[b] += sc[b][kk] * w;
    }
#pragma unroll
    for (int b = 0; b < 8; b++) atomicAdd(&ada[(size_t)b * 6144 + col], acc[b]);
}

// ---------------------------------------------------------------------------
// h = modulate(LN(x), shift, scale)  -> bf16
// ---------------------------------------------------------------------------
__global__ __launch_bounds__(256) void ln_mod_k(const float* __restrict__ X,
                                                const float* __restrict__ ada,
                                                int shoff, int scoff,
                                                bf16* __restrict__ Hout) {
    const int row = blockIdx.x;
    const int b   = row >> 10;
    const int tid = threadIdx.x;
    const float4 v = ((const float4*)(X + (size_t)row * C_))[tid];
    float s  = v.x + v.y + v.z + v.w;
    float sq = v.x * v.x + v.y * v.y + v.z * v.z + v.w * v.w;
#pragma unroll
    for (int off = 32; off; off >>= 1) {
        s  += __shfl_xor(s,  off);
        sq += __shfl_xor(sq, off);
    }
    __shared__ float rs_[4], rq_[4];
    if ((tid & 63) == 0) { rs_[tid >> 6] = s; rq_[tid >> 6] = sq; }
    __syncthreads();
    s  = rs_[0] + rs_[1] + rs_[2] + rs_[3];
    sq = rq_[0] + rq_[1] + rq_[2] + rq_[3];
    const float mu   = s * (1.f / 1024.f);
    const float var  = sq * (1.f / 1024.f) - mu * mu;
    const float rstd = rsqrtf(var + 1e-6f);
    const float4 scv = ((const float4*)(ada + (size_t)b * 6144 + scoff))[tid];
    const float4 shv = ((const float4*)(ada + (size_t)b * 6144 + shoff))[tid];
    bf16x4 o;
    o[0] = (bf16)(((v.x - mu) * rstd) * (1.f + scv.x) + shv.x);
    o[1] = (bf16)(((v.y - mu) * rstd) * (1.f + scv.y) + shv.y);
    o[2] = (bf16)(((v.z - mu) * rstd) * (1.f + scv.z) + shv.z);
    o[3] = (bf16)(((v.w - mu) * rstd) * (1.f + scv.w) + shv.w);
    *(bf16x4*)(Hout + (size_t)row * C_ + tid * 4) = o;
}

// ---------------------------------------------------------------------------
// 256x256-tile 8-wave phase-interleaved GEMM (T2+T3+T4+T5 port).
// BK=64 split into 2x 32-k phases. LDS: 2 dbuf x 2 ksub x (256x32) for A and
// B = 128 KiB. Per phase: issue 4 global_load_lds (prefetch, one K-tile i.e.
// TWO phases ahead of consumption) -> 12 ds_read_b128 -> barrier -> 32 MFMA
// under setprio(1) -> s_waitcnt vmcnt(4) -> barrier. The counted vmcnt keeps
// 4 loads in flight across every barrier (never drains to 0 in main loop).
// LDS chunk swizzle: physical 16B chunk c of row r holds logical chunk
// c ^ (r&3); applied on the (per-lane) global source so the gload_lds dest
// stays linear, and on the ds_read address. Conflict-free reads.
// MODE 2: bf16 out = v + bias      MODE 3: bf16 out = gelu(v + bias)
// ---------------------------------------------------------------------------
template <int MODE>
__global__ __launch_bounds__(512, 2) void gemm256_k(const bf16* __restrict__ A,
                                                    const bf16* __restrict__ Bt,
                                                    const float* __restrict__ bias,
                                                    bf16* __restrict__ outB,
                                                    int Ncols, int K, int GX) {
    __shared__ __attribute__((aligned(16))) bf16 As[2][2][256][32];
    __shared__ __attribute__((aligned(16))) bf16 Bs[2][2][256][32];

    const int tid  = threadIdx.x;
    const int lane = tid & 63, wave = tid >> 6;
    const int lrow = lane & 15, quad = lane >> 4;
    const int wm = wave >> 2, wn = wave & 3;          // 2 x 4 wave grid

    // bijective XCD-chunked swizzle (gridDim.x % 8 == 0), N-minor in chunk
    const unsigned lid = blockIdx.x;
    const unsigned cpx = gridDim.x >> 3;
    const unsigned g   = (lid & 7) * cpx + (lid >> 3);
    const size_t bm = (size_t)(g / GX) * 256;
    const size_t bn = (size_t)(g % GX) * 256;

    // staging source (pre-swizzled global addresses; linear LDS dest)
    const int r0 = tid >> 2;                          // 0..127
    const int cs = ((tid & 3) ^ (r0 & 3)) * 8;        // swizzled 16B chunk
    const bf16* gA0 = A  + (bm + r0) * (size_t)K + cs;
    const bf16* gA1 = gA0 + (size_t)128 * K;
    const bf16* gB0 = Bt + (bn + r0) * (size_t)K + cs;
    const bf16* gB1 = gB0 + (size_t)128 * K;

    f32x4 acc[8][4];
#pragma unroll
    for (int i = 0; i < 8; i++)
#pragma unroll
        for (int j = 0; j < 4; j++) acc[i][j] = (f32x4){0.f, 0.f, 0.f, 0.f};

    auto stage = [&](int bb, int ks, int koff) {
        bf16* la = &As[bb][ks][0][0] + wave * 512;
        bf16* lb = &Bs[bb][ks][0][0] + wave * 512;
        gload16(gA0 + koff, la);
        gload16(gA1 + koff, la + 4096);
        gload16(gB0 + koff, lb);
        gload16(gB1 + koff, lb + 4096);
    };

    const int xo = (quad ^ (lrow & 3)) * 8;           // read-side swizzle

    auto compute = [&](int bb, int ks) {
        const bf16(*Ap)[32] = As[bb][ks];
        const bf16(*Bp)[32] = Bs[bb][ks];
        bf16x8 bq[4], af[8];
#pragma unroll
        for (int ni = 0; ni < 4; ni++)
            bq[ni] = *(const bf16x8*)&Bp[wn * 64 + ni * 16 + lrow][xo];
#pragma unroll
        for (int mi = 0; mi < 8; mi++)
            af[mi] = *(const bf16x8*)&Ap[wm * 128 + mi * 16 + lrow][xo];
        __builtin_amdgcn_s_barrier();
        __builtin_amdgcn_s_setprio(1);
#pragma unroll
        for (int mi = 0; mi < 8; mi++)
#pragma unroll
            for (int ni = 0; ni < 4; ni++)
                acc[mi][ni] = mfma16(af[mi], bq[ni], acc[mi][ni]);
        __builtin_amdgcn_s_setprio(0);
    };

    // prologue: stage tile 0 (both k-halves) into buf 0
    stage(0, 0, 0);
    stage(0, 1, 32);
    asm volatile("s_waitcnt vmcnt(4)" ::: "memory");  // ks0 landed
    __builtin_amdgcn_s_barrier();

    const int KT = K >> 6;
    for (int kt = 0; kt < KT - 1; ++kt) {
        const int b  = kt & 1;
        const int kn = (kt + 1) << 6;
        // phase 1: prefetch next-tile ks0, compute (b, ks0)
        stage(b ^ 1, 0, kn);
        compute(b, 0);
        asm volatile("s_waitcnt vmcnt(4)" ::: "memory");  // this tile ks1 landed
        __builtin_amdgcn_s_barrier();
        // phase 2: prefetch next-tile ks1, compute (b, ks1)
        stage(b ^ 1, 1, kn + 32);
        compute(b, 1);
        asm volatile("s_waitcnt vmcnt(4)" ::: "memory");  // next tile ks0 landed
        __builtin_amdgcn_s_barrier();
    }
    {   // epilogue tile: no prefetch
        const int b = (KT - 1) & 1;
        compute(b, 0);
        asm volatile("s_waitcnt vmcnt(0)" ::: "memory");  // ks1 landed
        __builtin_amdgcn_s_barrier();
        compute(b, 1);
    }

    // C write
#pragma unroll
    for (int mi = 0; mi < 8; mi++) {
#pragma unroll
        for (int ni = 0; ni < 4; ni++) {
            const size_t gcol = bn + wn * 64 + ni * 16 + lrow;
            const float bv = bias[gcol];
#pragma unroll
            for (int r = 0; r < 4; r++) {
                const size_t grow = bm + wm * 128 + mi * 16 + quad * 4 + r;
                float v = acc[mi][ni][r] + bv;
                if (MODE == 3) {
                    float z = 1.59576912f * (v + 0.044715f * v * v * v);
                    v = v / (1.f + __expf(-z));
                }
                outB[grow * Ncols + gcol] = (bf16)v;
            }
        }
    }
}

// ---------------------------------------------------------------------------
// Generic bf16 MFMA GEMM: m97 structure + LDS XOR swizzle + XCD-local grid
// + in-block split-K (KS) + DOUBLE-BUFFERED K-loop. (kept for the N=1024
// projections and fc2, whose 256-tile grids would under-fill the chip)
// MODE 1: fp32 out = v + resid    MODE 2: bf16 out = v    MODE 3: bf16 gelu(v)
// ---------------------------------------------------------------------------
template <int MODE, int KS>
__global__ __launch_bounds__(256 * KS) void gemm_k(const bf16* __restrict__ A,
                                                   const bf16* __restrict__ Bt,
                                                   const float* __restrict__ bias,
                                                   const float* resid,
                                                   float* outF, bf16* outB,
                                                   int Ncols, int K, int GX) {
    __shared__ __attribute__((aligned(16))) bf16 As[2][KS][128][32];
    __shared__ __attribute__((aligned(16))) bf16 Bs[2][KS][128][32];
    const int tid  = threadIdx.x & 255;     // within-group thread id
    const int grp  = threadIdx.x >> 8;      // k-group (0..KS-1)
    const int lane = tid & 63, wave = tid >> 6;
    const int lrow = lane & 15, quad = lane >> 4;
    const int wm = wave >> 1, wn = wave & 1;

    // XCD-locality block swizzle
    const unsigned lid = blockIdx.x;
    const unsigned xcd = lid & 7, s = lid >> 3;
    const unsigned bnb = s % GX, bmb = (s / GX) * 8 + xcd;
    const size_t bm = (size_t)bmb * 128;
    const size_t bn = (size_t)bnb * 128;

    const int Kh = K / KS;                  // per-group K extent
    // staging: physical (prow, pseg) holds global k-seg pseg ^ ((prow>>1)&3)
    const int prow = tid >> 2, pseg = tid & 3;
    const int gseg = pseg ^ ((prow >> 1) & 3);
    const bf16* gA0 = A  + (bm + prow) * (size_t)K + grp * Kh + gseg * 8;
    const bf16* gA1 = gA0 + (size_t)64 * K;
    const bf16* gB0 = Bt + (bn + prow) * (size_t)K + grp * Kh + gseg * 8;
    const bf16* gB1 = gB0 + (size_t)64 * K;
    const int bufoff = KS * 128 * 32;       // elements per buffer
    bf16* lA = &As[0][grp][0][0] + wave * 512;
    bf16* lB = &Bs[0][grp][0][0] + wave * 512;

    // read-side swizzled chunk offset
    const int xoff = (quad ^ ((lrow >> 1) & 3)) * 8;

    f32x4 acc[4][4];
#pragma unroll
    for (int i = 0; i < 4; i++)
#pragma unroll
        for (int j = 0; j < 4; j++) acc[i][j] = (f32x4){0.f, 0.f, 0.f, 0.f};

    // prologue: stage iter 0 into buf 0
    {
        gload16(gA0, lA);
        gload16(gA1, lA + 2048);
        gload16(gB0, lB);
        gload16(gB1, lB + 2048);
    }
    int p = 0;
    for (int ko = 0; ko < Kh; ko += 32) {
        __syncthreads();                    // buf p staged (drain had MFMA phase in flight)
        if (ko + 32 < Kh) {                 // prefetch next iter into buf p^1
            const int po = (p ^ 1) * bufoff;
            gload16(gA0 + ko + 32, lA + po);
            gload16(gA1 + ko + 32, lA + po + 2048);
            gload16(gB0 + ko + 32, lB + po);
            gload16(gB1 + ko + 32, lB + po + 2048);
        }
        const bf16(*Asp)[32] = As[p][grp];
        const bf16(*Bsp)[32] = Bs[p][grp];
        bf16x8 af[4], bfr[4];
#pragma unroll
        for (int mi = 0; mi < 4; mi++)
            af[mi] = *(const bf16x8*)&Asp[wm * 64 + mi * 16 + lrow][xoff];
#pragma unroll
        for (int ni = 0; ni < 4; ni++)
            bfr[ni] = *(const bf16x8*)&Bsp[wn * 64 + ni * 16 + lrow][xoff];
#pragma unroll
        for (int mi = 0; mi < 4; mi++)
#pragma unroll
            for (int ni = 0; ni < 4; ni++)
                acc[mi][ni] = mfma16(af[mi], bfr[ni], acc[mi][ni]);
        p ^= 1;
    }

    // in-block split-K reduction: group 1 -> LDS (As region) -> group 0.
    if constexpr (KS == 2) {
        f32x4* red = (f32x4*)&As[0][0][0][0];   // 16 KB region
#pragma unroll
        for (int rnd = 0; rnd < 4; rnd++) {
            __syncthreads();
            if (grp == 1) {
#pragma unroll
                for (int c = 0; c < 4; c++) {
                    const int idx = rnd * 4 + c;
                    red[c * 256 + tid] = acc[idx >> 2][idx & 3];
                }
            }
            __syncthreads();
            if (grp == 0) {
#pragma unroll
                for (int c = 0; c < 4; c++) {
                    const int idx = rnd * 4 + c;
                    acc[idx >> 2][idx & 3] += red[c * 256 + tid];
                }
            }
        }
    }

    if (grp == 0) {
#pragma unroll
        for (int mi = 0; mi < 4; mi++) {
#pragma unroll
            for (int ni = 0; ni < 4; ni++) {
                const size_t gcol = bn + wn * 64 + ni * 16 + lrow;
                const float bv = bias[gcol];
#pragma unroll
                for (int r = 0; r < 4; r++) {
                    const size_t grow = bm + wm * 64 + mi * 16 + quad * 4 + r;
                    const size_t idx  = grow * Ncols + gcol;
                    float v = acc[mi][ni][r] + bv;
                    if (MODE == 1) {
                        outF[idx] = v + resid[idx];
                    } else if (MODE == 2) {
                        outB[idx] = (bf16)v;
                    } else {
                        float z = 1.59576912f * (v + 0.044715f * v * v * v);
                        outB[idx] = (bf16)(v / (1.f + __expf(-z)));
                    }
                }
            }
        }
    }
}

// ---------------------------------------------------------------------------
// Flash attention, S^T formulation. D=64, 64-key chunks. (unchanged)
// ---------------------------------------------------------------------------
template <bool MASKED>
__global__ __launch_bounds__(256) void attn_k(const bf16* __restrict__ Qp, int qstride,
                                              const bf16* __restrict__ Kp, int kstride,
                                              const bf16* __restrict__ Vtg,
                                              const int* __restrict__ mask, int Mk,
                                              bf16* __restrict__ O) {
    __shared__ __attribute__((aligned(16))) bf16 Kt[64][88];      // [key][d]
    __shared__ __attribute__((aligned(16))) bf16 Vt[64][88];      // [d][key]
    __shared__ __attribute__((aligned(16))) bf16 Pt[4][16][88];   // [wave][q][key]
    __shared__ float madd[64];

    const int b = blockIdx.z, h = blockIdx.y;
    const int tid  = threadIdx.x;
    const int lane = tid & 63, wave = tid >> 6;
    const int lrow = lane & 15, quad = lane >> 4;
    const int q0 = blockIdx.x * 64 + wave * 16;

    const bf16* qp = Qp + ((size_t)(b * N_ + q0 + lrow)) * qstride + h * 64 + quad * 8;
    const bf16x8 bq0 = *(const bf16x8*)(qp);
    const bf16x8 bq1 = *(const bf16x8*)(qp + 32);

    f32x4 acc[4];
#pragma unroll
    for (int t = 0; t < 4; t++) acc[t] = (f32x4){0.f, 0.f, 0.f, 0.f};
    float mrun = -3e38f, lrun = 0.f;

    const int srow = tid >> 2;
    const int sseg = (tid & 3) * 16;

    const bf16* kbase = Kp + ((size_t)b * Mk + srow) * kstride + h * 64 + sseg;
    const bf16* vbase = Vtg + ((size_t)(b * 1024 + h * 64 + srow)) * Mk + sseg;

    for (int kc = 0; kc < Mk; kc += 64) {
        __syncthreads();
        const bf16* kp = kbase + (size_t)kc * kstride;
        bf16x8 k0 = *(const bf16x8*)kp;
        bf16x8 k1 = *(const bf16x8*)(kp + 8);
        *(bf16x8*)&Kt[srow][sseg]     = k0;
        *(bf16x8*)&Kt[srow][sseg + 8] = k1;
        const bf16* vp = vbase + kc;
        bf16x8 v0 = *(const bf16x8*)vp;
        bf16x8 v1 = *(const bf16x8*)(vp + 8);
        *(bf16x8*)&Vt[srow][sseg]     = v0;
        *(bf16x8*)&Vt[srow][sseg + 8] = v1;
        if (MASKED && tid < 64)
            madd[tid] = (mask[b * Mk + kc + tid] == 0) ? -1e30f : 0.f;
        __syncthreads();

        float sv[4][4];
#pragma unroll
        for (int t = 0; t < 4; t++) {
            f32x4 s = (f32x4){0.f, 0.f, 0.f, 0.f};
            bf16x8 ak0 = *(const bf16x8*)&Kt[t * 16 + lrow][quad * 8];
            s = mfma16(ak0, bq0, s);
            bf16x8 ak1 = *(const bf16x8*)&Kt[t * 16 + lrow][32 + quad * 8];
            s = mfma16(ak1, bq1, s);
#pragma unroll
            for (int r = 0; r < 4; r++) {
                float ma = MASKED ? madd[t * 16 + quad * 4 + r] : 0.f;
                sv[t][r] = s[r] * 0.125f + ma;
            }
        }

        float vmax = sv[0][0];
#pragma unroll
        for (int t = 0; t < 4; t++)
#pragma unroll
            for (int r = 0; r < 4; r++) vmax = fmaxf(vmax, sv[t][r]);
        vmax = fmaxf(vmax, __shfl_xor(vmax, 16));
        vmax = fmaxf(vmax, __shfl_xor(vmax, 32));
        const float mnew  = fmaxf(mrun, vmax);
        const float alpha = __expf(mrun - mnew);
        mrun = mnew;
        float rsum = 0.f;
#pragma unroll
        for (int t = 0; t < 4; t++) {
            bf16x4 p4;
#pragma unroll
            for (int r = 0; r < 4; r++) {
                float p = __expf(sv[t][r] - mnew);
                rsum += p;
                p4[r] = (bf16)p;
            }
            *(bf16x4*)&Pt[wave][lrow][t * 16 + quad * 4] = p4;
        }
        rsum += __shfl_xor(rsum, 16);
        rsum += __shfl_xor(rsum, 32);
        lrun = lrun * alpha + rsum;

        float alpha4[4];
#pragma unroll
        for (int r = 0; r < 4; r++) alpha4[r] = __shfl(alpha, quad * 4 + r);
#pragma unroll
        for (int t = 0; t < 4; t++)
#pragma unroll
            for (int r = 0; r < 4; r++) acc[t][r] *= alpha4[r];

        __syncthreads();
        const bf16x8 ap0 = *(const bf16x8*)&Pt[wave][lrow][quad * 8];
        const bf16x8 ap1 = *(const bf16x8*)&Pt[wave][lrow][32 + quad * 8];

#pragma unroll
        for (int t = 0; t < 4; t++) {
            bf16x8 bv0 = *(const bf16x8*)&Vt[t * 16 + lrow][quad * 8];
            acc[t] = mfma16(ap0, bv0, acc[t]);
            bf16x8 bv1 = *(const bf16x8*)&Vt[t * 16 + lrow][32 + quad * 8];
            acc[t] = mfma16(ap1, bv1, acc[t]);
        }
    }

    float linv = 1.f / lrun;
    float linv4[4];
#pragma unroll
    for (int r = 0; r < 4; r++) linv4[r] = __shfl(linv, quad * 4 + r);
#pragma unroll
    for (int r = 0; r < 4; r++) {
        const size_t grow = (size_t)(b * N_ + q0 + quad * 4 + r);
#pragma unroll
        for (int t = 0; t < 4; t++)
            O[grow * C_ + h * 64 + t * 16 + lrow] = (bf16)(acc[t][r] * linv4[r]);
    }
}

// ---------------------------------------------------------------------------
extern "C" void kernel_launch(void* const* d_in, const int* in_sizes, int n_in,
                              void* d_out, int out_size, void* d_ws, size_t ws_size,
                              hipStream_t stream) {
    const float* x     = (const float*)d_in[0];
    const float* cdino = (const float*)d_in[1];
    const float* ctext = (const float*)d_in[2];
    const int*   tmask = (const int*)d_in[3];
    const float* W_ada = (const float*)d_in[4];
    const float* b_ada = (const float*)d_in[5];
    const float* W_qkv = (const float*)d_in[6];
    const float* b_qkv = (const float*)d_in[7];
    const float* W_sa  = (const float*)d_in[8];
    const float* b_sa  = (const float*)d_in[9];
    const float* W_q   = (const float*)d_in[10];
    const float* b_q   = (const float*)d_in[11];
    const float* W_kv  = (const float*)d_in[12];
    const float* b_kv  = (const float*)d_in[13];
    const float* W_ca  = (const float*)d_in[14];
    const float* b_ca  = (const float*)d_in[15];
    const float* W_fc1 = (const float*)d_in[16];
    const float* b_fc1 = (const float*)d_in[17];
    const float* W_fc2 = (const float*)d_in[18];
    const float* b_fc2 = (const float*)d_in[19];
    float* out = (float*)d_out;

    char* ws = (char*)d_ws;
    size_t off = 0;
    auto alloc = [&](size_t bytes) -> char* {
        char* p = ws + off;
        off += (bytes + 255) & ~(size_t)255;
        return p;
    };
    float* ada  = (float*)alloc((size_t)8 * 6144 * 4);
    bf16* ctxb  = (bf16*)alloc((size_t)1024 * 1024 * 2);
    bf16* WqkvT = (bf16*)alloc((size_t)3072 * 1024 * 2);
    bf16* WsaT  = (bf16*)alloc((size_t)1024 * 1024 * 2);
    bf16* WqT   = (bf16*)alloc((size_t)1024 * 1024 * 2);
    bf16* WkvT  = (bf16*)alloc((size_t)2048 * 1024 * 2);
    bf16* WcaT  = (bf16*)alloc((size_t)1024 * 1024 * 2);
    bf16* Wfc1T = (bf16*)alloc((size_t)4096 * 1024 * 2);
    bf16* Wfc2T = (bf16*)alloc((size_t)1024 * 4096 * 2);
    float* xbuf = (float*)alloc((size_t)8192 * 1024 * 4);
    bf16* hbuf  = (bf16*)alloc((size_t)8192 * 1024 * 2);
    bf16* attnb = (bf16*)alloc((size_t)8192 * 1024 * 2);
    bf16* VtgSA = (bf16*)alloc((size_t)8192 * 1024 * 2);
    bf16* VtgCA = (bf16*)alloc((size_t)8192 * 128 * 2);
    bf16* pool  = (bf16*)alloc((size_t)8192 * 4096 * 2);
    if (off > ws_size) return;

    bf16* qkvb  = pool;
    bf16* qb    = pool;
    bf16* kvb   = pool + (size_t)8192 * 1024;
    bf16* gelub = pool;

    // --- weight prep ---
    transpose_k<<<dim3(3072 / 32, 1024 / 32), 256, 0, stream>>>(W_qkv, WqkvT, 1024, 3072);
    transpose_k<<<dim3(1024 / 32, 1024 / 32), 256, 0, stream>>>(W_sa,  WsaT,  1024, 1024);
    transpose_k<<<dim3(1024 / 32, 1024 / 32), 256, 0, stream>>>(W_q,   WqT,   1024, 1024);
    transpose_k<<<dim3(2048 / 32, 1024 / 32), 256, 0, stream>>>(W_kv,  WkvT,  1024, 2048);
    transpose_k<<<dim3(1024 / 32, 1024 / 32), 256, 0, stream>>>(W_ca,  WcaT,  1024, 1024);
    transpose_k<<<dim3(4096 / 32, 1024 / 32), 256, 0, stream>>>(W_fc1, Wfc1T, 1024, 4096);
    transpose_k<<<dim3(1024 / 32, 4096 / 32), 256, 0, stream>>>(W_fc2, Wfc2T, 4096, 1024);
    cvt_bf16_k<<<1024, 256, 0, stream>>>(ctext, ctxb, 262144);

    // --- ada ---
    ada_init_k<<<192, 256, 0, stream>>>(b_ada, ada);
    ada_k<<<dim3(24, 32), 256, 0, stream>>>(cdino, W_ada, ada);

    // --- self-attention ---
    ln_mod_k<<<8192, 256, 0, stream>>>(x, ada, 0, 1024, hbuf);
    gemm256_k<2><<<32 * 12, 512, 0, stream>>>(hbuf, WqkvT, b_qkv, qkvb, 3072, 1024, 12);
    vtrans_k<<<dim3(32, 32, 8), 256, 0, stream>>>(qkvb, 3072, 2048, 1024, VtgSA);
    attn_k<false><<<dim3(16, 16, 8), 256, 0, stream>>>(qkvb, 3072, qkvb + 1024, 3072, VtgSA,
                                                       nullptr, 1024, attnb);
    gemm_k<1, 2><<<8 * 64, 512, 0, stream>>>(attnb, WsaT, b_sa, x, xbuf, nullptr, 1024, 1024, 8);

    // --- cross-attention ---
    ln_mod_k<<<8192, 256, 0, stream>>>(xbuf, ada, 2048, 3072, hbuf);
    gemm_k<2, 2><<<8 * 64, 512, 0, stream>>>(hbuf, WqT, b_q, nullptr, nullptr, qb, 1024, 1024, 8);
    gemm_k<2, 2><<<16 * 8, 512, 0, stream>>>(ctxb, WkvT, b_kv, nullptr, nullptr, kvb, 2048, 1024, 16);
    vtrans_k<<<dim3(4, 32, 8), 256, 0, stream>>>(kvb, 2048, 1024, 128, VtgCA);
    attn_k<true><<<dim3(16, 16, 8), 256, 0, stream>>>(qb, 1024, kvb, 2048, VtgCA,
                                                      tmask, 128, attnb);
    gemm_k<1, 2><<<8 * 64, 512, 0, stream>>>(attnb, WcaT, b_ca, xbuf, xbuf, nullptr, 1024, 1024, 8);

    // --- MLP ---
    ln_mod_k<<<8192, 256, 0, stream>>>(xbuf, ada, 4096, 5120, hbuf);
    gemm256_k<3><<<32 * 16, 512, 0, stream>>>(hbuf, Wfc1T, b_fc1, gelub, 4096, 1024, 16);
    gemm_k<1, 2><<<8 * 64, 512, 0, stream>>>(gelub, Wfc2T, b_fc2, xbuf, out, nullptr, 1024, 4096, 8);
}

// Round 6
// 727.997 us; speedup vs baseline: 1.0205x; 1.0205x over previous
//
#include <hip/hip_runtime.h>
#include <hip/hip_bf16.h>

// Problem constants
#define B_   8
#define N_   1024
#define M_   128
#define C_   1024
#define H_   16
#define D_   64
#define MLP_ 4096

typedef __bf16 bf16;
typedef __bf16 bf16x8 __attribute__((ext_vector_type(8)));
typedef __bf16 bf16x4 __attribute__((ext_vector_type(4)));
typedef float  f32x4  __attribute__((ext_vector_type(4)));

__device__ __forceinline__ f32x4 mfma16(bf16x8 a, bf16x8 b, f32x4 c) {
    return __builtin_amdgcn_mfma_f32_16x16x32_bf16(a, b, c, 0, 0, 0);
}

// async global->LDS, 16 B per lane (LDS dest wave-uniform base + lane*16)
__device__ __forceinline__ void gload16(const bf16* g, bf16* l) {
    __builtin_amdgcn_global_load_lds(
        (const __attribute__((address_space(1))) void*)g,
        (__attribute__((address_space(3))) void*)l, 16, 0, 0);
}

// ---------------------------------------------------------------------------
// Weight transpose + fp32->bf16:  W (K x Nc) fp32  ->  Wt (Nc x K) bf16
// ---------------------------------------------------------------------------
__global__ __launch_bounds__(256) void transpose_k(const float* __restrict__ W,
                                                   bf16* __restrict__ Wt,
                                                   int K, int Nc) {
    __shared__ float tile[32][33];
    const int x  = threadIdx.x & 31;
    const int y0 = threadIdx.x >> 5;
    const size_t n0 = (size_t)blockIdx.x * 32;
    const size_t k0 = (size_t)blockIdx.y * 32;
#pragma unroll
    for (int i = 0; i < 4; i++)
        tile[y0 + i * 8][x] = W[(k0 + y0 + i * 8) * Nc + n0 + x];
    __syncthreads();
#pragma unroll
    for (int i = 0; i < 4; i++)
        Wt[(n0 + y0 + i * 8) * K + k0 + x] = (bf16)tile[x][y0 + i * 8];
}

// bf16 V transpose: in rows (b*Mk + m), cols coff+hd -> outT[(b*1024+hd)*Mk + m]
__global__ __launch_bounds__(256) void vtrans_k(const bf16* __restrict__ in, int instride,
                                                int coff, int Mk, bf16* __restrict__ outT) {
    __shared__ bf16 t[32][33];
    const int tx = threadIdx.x & 31;
    const int ty0 = threadIdx.x >> 5;
    const int m0  = blockIdx.x * 32;
    const int hd0 = blockIdx.y * 32;
    const int b   = blockIdx.z;
#pragma unroll
    for (int i = 0; i < 4; i++)
        t[ty0 + i * 8][tx] = in[((size_t)(b * Mk + m0 + ty0 + i * 8)) * instride + coff + hd0 + tx];
    __syncthreads();
#pragma unroll
    for (int i = 0; i < 4; i++)
        outT[((size_t)(b * 1024 + hd0 + ty0 + i * 8)) * Mk + m0 + tx] = t[tx][ty0 + i * 8];
}

// fp32 -> bf16 elementwise (n4 = count/4)
__global__ __launch_bounds__(256) void cvt_bf16_k(const float* __restrict__ in,
                                                  bf16* __restrict__ out, int n4) {
    int i = blockIdx.x * 256 + threadIdx.x;
    if (i < n4) {
        float4 v = ((const float4*)in)[i];
        bf16x4 o;
        o[0] = (bf16)v.x; o[1] = (bf16)v.y; o[2] = (bf16)v.z; o[3] = (bf16)v.w;
        ((bf16x4*)out)[i] = o;
    }
}

// ---------------------------------------------------------------------------
// ada = silu(c_dino) @ W_ada + b_ada   (8 x 6144) fp32, split-K with atomics.
// ---------------------------------------------------------------------------
__global__ __launch_bounds__(256) void ada_init_k(const float* __restrict__ bias,
                                                  float* __restrict__ ada) {
    int i = blockIdx.x * 256 + threadIdx.x;
    ada[i] = bias[i % 6144];
}

__global__ __launch_bounds__(256) void ada_k(const float* __restrict__ cdino,
                                             const float* __restrict__ W,
                                             float* __restrict__ ada) {
    __shared__ float sc[8][32];
    const int tid = threadIdx.x;
    const int k0  = blockIdx.y * 32;
    {
        float c = cdino[(tid >> 5) * 1024 + k0 + (tid & 31)];
        sc[tid >> 5][tid & 31] = c / (1.f + __expf(-c));
    }
    __syncthreads();
    const int col = blockIdx.x * 256 + tid;
    float acc[8];
#pragma unroll
    for (int b = 0; b < 8; b++) acc[b] = 0.f;
    for (int kk = 0; kk < 32; kk++) {
        float w = W[(size_t)(k0 + kk) * 6144 + col];
#pragma unroll
        for (int b = 0; b < 8; b++) acc[b] += sc[b][kk] * w;
    }
#pragma unroll
    for (int b = 0; b < 8; b++) atomicAdd(&ada[(size_t)b * 6144 + col], acc[b]);
}

// ---------------------------------------------------------------------------
// h = modulate(LN(x), shift, scale)  -> bf16
// ---------------------------------------------------------------------------
__global__ __launch_bounds__(256) void ln_mod_k(const float* __restrict__ X,
                                                const float* __restrict__ ada,
                                                int shoff, int scoff,
                                                bf16* __restrict__ Hout) {
    const int row = blockIdx.x;
    const int b   = row >> 10;
    const int tid = threadIdx.x;
    const float4 v = ((const float4*)(X + (size_t)row * C_))[tid];
    float s  = v.x + v.y + v.z + v.w;
    float sq = v.x * v.x + v.y * v.y + v.z * v.z + v.w * v.w;
#pragma unroll
    for (int off = 32; off; off >>= 1) {
        s  += __shfl_xor(s,  off);
        sq += __shfl_xor(sq, off);
    }
    __shared__ float rs_[4], rq_[4];
    if ((tid & 63) == 0) { rs_[tid >> 6] = s; rq_[tid >> 6] = sq; }
    __syncthreads();
    s  = rs_[0] + rs_[1] + rs_[2] + rs_[3];
    sq = rq_[0] + rq_[1] + rq_[2] + rq_[3];
    const float mu   = s * (1.f / 1024.f);
    const float var  = sq * (1.f / 1024.f) - mu * mu;
    const float rstd = rsqrtf(var + 1e-6f);
    const float4 scv = ((const float4*)(ada + (size_t)b * 6144 + scoff))[tid];
    const float4 shv = ((const float4*)(ada + (size_t)b * 6144 + shoff))[tid];
    bf16x4 o;
    o[0] = (bf16)(((v.x - mu) * rstd) * (1.f + scv.x) + shv.x);
    o[1] = (bf16)(((v.y - mu) * rstd) * (1.f + scv.y) + shv.y);
    o[2] = (bf16)(((v.z - mu) * rstd) * (1.f + scv.z) + shv.z);
    o[3] = (bf16)(((v.w - mu) * rstd) * (1.f + scv.w) + shv.w);
    *(bf16x4*)(Hout + (size_t)row * C_ + tid * 4) = o;
}

// ---------------------------------------------------------------------------
// 256x256-tile 8-wave GEMM, quadrant-phase schedule (m201-style).
// LDS: 2 dbuf x 2 ksub x [256][32] for A and B = 128 KiB. Each K-tile (64 k)
// runs 4 phases: {4-8 ds_read_b128 (+2x2 global_load_lds in P0/P2) ->
// barrier -> 16 MFMA under setprio -> barrier}, with counted vmcnt(4) only
// at P1/P3 ends (loads never drain to 0 in the main loop).
// Bank-slot swizzle (64 B rows -> slot = (row&1)*4 + chunk): physical chunk
// c of row r holds logical chunk c ^ ((r>>1)&3). Consecutive 8-lane groups
// then hit all 8 slots exactly once -> conflict-free (pattern measured 0
// conflicts in gemm_k). Applied on the pre-swizzled global source (linear
// gload_lds dest) and on the ds_read address.
// MODE 2: bf16 out = v + bias      MODE 3: bf16 out = gelu(v + bias)
// ---------------------------------------------------------------------------
template <int MODE>
__global__ __launch_bounds__(512, 2) void gemm256_k(const bf16* __restrict__ A,
                                                    const bf16* __restrict__ Bt,
                                                    const float* __restrict__ bias,
                                                    bf16* __restrict__ outB,
                                                    int Ncols, int K, int GX) {
    __shared__ __attribute__((aligned(16))) bf16 As[2][2][256][32];
    __shared__ __attribute__((aligned(16))) bf16 Bs[2][2][256][32];

    const int tid  = threadIdx.x;
    const int lane = tid & 63, wave = tid >> 6;
    const int lrow = lane & 15, quad = lane >> 4;
    const int wm = wave >> 2, wn = wave & 3;          // 2 x 4 wave grid

    // bijective XCD-chunked swizzle (gridDim.x % 8 == 0), N-minor in chunk
    const unsigned lid = blockIdx.x;
    const unsigned cpx = gridDim.x >> 3;
    const unsigned g   = (lid & 7) * cpx + (lid >> 3);
    const size_t bm = (size_t)(g / GX) * 256;
    const size_t bn = (size_t)(g % GX) * 256;

    // staging source (pre-swizzled global addresses; linear LDS dest)
    const int r0 = tid >> 2;                          // 0..127
    const int cs = ((tid & 3) ^ ((r0 >> 1) & 3)) * 8; // swizzled 16B chunk
    const bf16* gA0 = A  + (bm + r0) * (size_t)K + cs;
    const bf16* gA1 = gA0 + (size_t)128 * K;
    const bf16* gB0 = Bt + (bn + r0) * (size_t)K + cs;
    const bf16* gB1 = gB0 + (size_t)128 * K;

    f32x4 acc[8][4];
#pragma unroll
    for (int i = 0; i < 8; i++)
#pragma unroll
        for (int j = 0; j < 4; j++) acc[i][j] = (f32x4){0.f, 0.f, 0.f, 0.f};

    auto stage = [&](int bb, int ks, int koff) {
        bf16* la = &As[bb][ks][0][0] + wave * 512;
        bf16* lb = &Bs[bb][ks][0][0] + wave * 512;
        gload16(gA0 + koff, la);
        gload16(gA1 + koff, la + 4096);
        gload16(gB0 + koff, lb);
        gload16(gB1 + koff, lb + 4096);
    };

    // read-side swizzle: mi*16 / h*64 / wm*128 row offsets are all 0 mod 8,
    // so (row>>1)&3 == (lrow>>1)&3 — lane-constant.
    const int xo = (quad ^ ((lrow >> 1) & 3)) * 8;

    bf16x8 bq[4], af[4];
    auto readB4 = [&](int bb, int ks) {
        const bf16(*Bp)[32] = Bs[bb][ks];
#pragma unroll
        for (int ni = 0; ni < 4; ni++)
            bq[ni] = *(const bf16x8*)&Bp[wn * 64 + ni * 16 + lrow][xo];
    };
    auto readA4 = [&](int bb, int ks, int h) {
        const bf16(*Ap)[32] = As[bb][ks];
#pragma unroll
        for (int mi = 0; mi < 4; mi++)
            af[mi] = *(const bf16x8*)&Ap[wm * 128 + h * 64 + mi * 16 + lrow][xo];
    };
    auto mfma16c = [&](int h) {
        __builtin_amdgcn_s_setprio(1);
#pragma unroll
        for (int mi = 0; mi < 4; mi++)
#pragma unroll
            for (int ni = 0; ni < 4; ni++)
                acc[h * 4 + mi][ni] = mfma16(af[mi], bq[ni], acc[h * 4 + mi][ni]);
        __builtin_amdgcn_s_setprio(0);
    };

    // prologue: stage tile 0 (both k-halves) into buf 0
    stage(0, 0, 0);
    stage(0, 1, 32);
    asm volatile("s_waitcnt vmcnt(4)" ::: "memory");  // S(0,ks0) landed
    __builtin_amdgcn_s_barrier();

    const int KT = K >> 6;
    for (int kt = 0; kt < KT - 1; ++kt) {
        const int b  = kt & 1;
        const int kn = (kt + 1) << 6;
        // P0: reads (b,ks0,h0)+B, prefetch next ks0, 16 MFMA
        readB4(b, 0); readA4(b, 0, 0);
        stage(b ^ 1, 0, kn);
        __builtin_amdgcn_s_barrier();
        mfma16c(0);
        __builtin_amdgcn_s_barrier();
        // P1: reads (b,ks0,h1), 16 MFMA; then S(kt,ks1) must be landed
        readA4(b, 0, 1);
        __builtin_amdgcn_s_barrier();
        mfma16c(1);
        asm volatile("s_waitcnt vmcnt(4)" ::: "memory");
        __builtin_amdgcn_s_barrier();
        // P2: reads (b,ks1,h0)+B, prefetch next ks1, 16 MFMA
        readB4(b, 1); readA4(b, 1, 0);
        stage(b ^ 1, 1, kn + 32);
        __builtin_amdgcn_s_barrier();
        mfma16c(0);
        __builtin_amdgcn_s_barrier();
        // P3: reads (b,ks1,h1), 16 MFMA; then S(kt+1,ks0) must be landed
        readA4(b, 1, 1);
        __builtin_amdgcn_s_barrier();
        mfma16c(1);
        asm volatile("s_waitcnt vmcnt(4)" ::: "memory");
        __builtin_amdgcn_s_barrier();
    }
    {   // epilogue tile: no prefetch
        const int b = (KT - 1) & 1;
        readB4(b, 0); readA4(b, 0, 0);
        __builtin_amdgcn_s_barrier();
        mfma16c(0);
        __builtin_amdgcn_s_barrier();
        readA4(b, 0, 1);
        __builtin_amdgcn_s_barrier();
        mfma16c(1);
        asm volatile("s_waitcnt vmcnt(0)" ::: "memory");  // S(last,ks1) landed
        __builtin_amdgcn_s_barrier();
        readB4(b, 1); readA4(b, 1, 0);
        __builtin_amdgcn_s_barrier();
        mfma16c(0);
        __builtin_amdgcn_s_barrier();
        readA4(b, 1, 1);
        __builtin_amdgcn_s_barrier();
        mfma16c(1);
    }

    // C write
#pragma unroll
    for (int mi = 0; mi < 8; mi++) {
#pragma unroll
        for (int ni = 0; ni < 4; ni++) {
            const size_t gcol = bn + wn * 64 + ni * 16 + lrow;
            const float bv = bias[gcol];
#pragma unroll
            for (int r = 0; r < 4; r++) {
                const size_t grow = bm + wm * 128 + mi * 16 + quad * 4 + r;
                float v = acc[mi][ni][r] + bv;
                if (MODE == 3) {
                    float z = 1.59576912f * (v + 0.044715f * v * v * v);
                    v = v / (1.f + __expf(-z));
                }
                outB[grow * Ncols + gcol] = (bf16)v;
            }
        }
    }
}

// ---------------------------------------------------------------------------
// Generic bf16 MFMA GEMM: m97 structure + LDS XOR swizzle + XCD-local grid
// + in-block split-K (KS) + DOUBLE-BUFFERED K-loop. (kept for the N=1024
// projections and fc2, whose 256-tile grids would under-fill the chip)
// MODE 1: fp32 out = v + resid    MODE 2: bf16 out = v    MODE 3: bf16 gelu(v)
// ---------------------------------------------------------------------------
template <int MODE, int KS>
__global__ __launch_bounds__(256 * KS) void gemm_k(const bf16* __restrict__ A,
                                                   const bf16* __restrict__ Bt,
                                                   const float* __restrict__ bias,
                                                   const float* resid,
                                                   float* outF, bf16* outB,
                                                   int Ncols, int K, int GX) {
    __shared__ __attribute__((aligned(16))) bf16 As[2][KS][128][32];
    __shared__ __attribute__((aligned(16))) bf16 Bs[2][KS][128][32];
    const int tid  = threadIdx.x & 255;     // within-group thread id
    const int grp  = threadIdx.x >> 8;      // k-group (0..KS-1)
    const int lane = tid & 63, wave = tid >> 6;
    const int lrow = lane & 15, quad = lane >> 4;
    const int wm = wave >> 1, wn = wave & 1;

    // XCD-locality block swizzle
    const unsigned lid = blockIdx.x;
    const unsigned xcd = lid & 7, s = lid >> 3;
    const unsigned bnb = s % GX, bmb = (s / GX) * 8 + xcd;
    const size_t bm = (size_t)bmb * 128;
    const size_t bn = (size_t)bnb * 128;

    const int Kh = K / KS;                  // per-group K extent
    // staging: physical (prow, pseg) holds global k-seg pseg ^ ((prow>>1)&3)
    const int prow = tid >> 2, pseg = tid & 3;
    const int gseg = pseg ^ ((prow >> 1) & 3);
    const bf16* gA0 = A  + (bm + prow) * (size_t)K + grp * Kh + gseg * 8;
    const bf16* gA1 = gA0 + (size_t)64 * K;
    const bf16* gB0 = Bt + (bn + prow) * (size_t)K + grp * Kh + gseg * 8;
    const bf16* gB1 = gB0 + (size_t)64 * K;
    const int bufoff = KS * 128 * 32;       // elements per buffer
    bf16* lA = &As[0][grp][0][0] + wave * 512;
    bf16* lB = &Bs[0][grp][0][0] + wave * 512;

    // read-side swizzled chunk offset
    const int xoff = (quad ^ ((lrow >> 1) & 3)) * 8;

    f32x4 acc[4][4];
#pragma unroll
    for (int i = 0; i < 4; i++)
#pragma unroll
        for (int j = 0; j < 4; j++) acc[i][j] = (f32x4){0.f, 0.f, 0.f, 0.f};

    // prologue: stage iter 0 into buf 0
    {
        gload16(gA0, lA);
        gload16(gA1, lA + 2048);
        gload16(gB0, lB);
        gload16(gB1, lB + 2048);
    }
    int p = 0;
    for (int ko = 0; ko < Kh; ko += 32) {
        __syncthreads();                    // buf p staged (drain had MFMA phase in flight)
        if (ko + 32 < Kh) {                 // prefetch next iter into buf p^1
            const int po = (p ^ 1) * bufoff;
            gload16(gA0 + ko + 32, lA + po);
            gload16(gA1 + ko + 32, lA + po + 2048);
            gload16(gB0 + ko + 32, lB + po);
            gload16(gB1 + ko + 32, lB + po + 2048);
        }
        const bf16(*Asp)[32] = As[p][grp];
        const bf16(*Bsp)[32] = Bs[p][grp];
        bf16x8 af[4], bfr[4];
#pragma unroll
        for (int mi = 0; mi < 4; mi++)
            af[mi] = *(const bf16x8*)&Asp[wm * 64 + mi * 16 + lrow][xoff];
#pragma unroll
        for (int ni = 0; ni < 4; ni++)
            bfr[ni] = *(const bf16x8*)&Bsp[wn * 64 + ni * 16 + lrow][xoff];
#pragma unroll
        for (int mi = 0; mi < 4; mi++)
#pragma unroll
            for (int ni = 0; ni < 4; ni++)
                acc[mi][ni] = mfma16(af[mi], bfr[ni], acc[mi][ni]);
        p ^= 1;
    }

    // in-block split-K reduction: group 1 -> LDS (As region) -> group 0.
    if constexpr (KS == 2) {
        f32x4* red = (f32x4*)&As[0][0][0][0];   // 16 KB region
#pragma unroll
        for (int rnd = 0; rnd < 4; rnd++) {
            __syncthreads();
            if (grp == 1) {
#pragma unroll
                for (int c = 0; c < 4; c++) {
                    const int idx = rnd * 4 + c;
                    red[c * 256 + tid] = acc[idx >> 2][idx & 3];
                }
            }
            __syncthreads();
            if (grp == 0) {
#pragma unroll
                for (int c = 0; c < 4; c++) {
                    const int idx = rnd * 4 + c;
                    acc[idx >> 2][idx & 3] += red[c * 256 + tid];
                }
            }
        }
    }

    if (grp == 0) {
#pragma unroll
        for (int mi = 0; mi < 4; mi++) {
#pragma unroll
            for (int ni = 0; ni < 4; ni++) {
                const size_t gcol = bn + wn * 64 + ni * 16 + lrow;
                const float bv = bias[gcol];
#pragma unroll
                for (int r = 0; r < 4; r++) {
                    const size_t grow = bm + wm * 64 + mi * 16 + quad * 4 + r;
                    const size_t idx  = grow * Ncols + gcol;
                    float v = acc[mi][ni][r] + bv;
                    if (MODE == 1) {
                        outF[idx] = v + resid[idx];
                    } else if (MODE == 2) {
                        outB[idx] = (bf16)v;
                    } else {
                        float z = 1.59576912f * (v + 0.044715f * v * v * v);
                        outB[idx] = (bf16)(v / (1.f + __expf(-z)));
                    }
                }
            }
        }
    }
}

// ---------------------------------------------------------------------------
// Flash attention, S^T formulation. D=64, 64-key chunks. (unchanged)
// ---------------------------------------------------------------------------
template <bool MASKED>
__global__ __launch_bounds__(256) void attn_k(const bf16* __restrict__ Qp, int qstride,
                                              const bf16* __restrict__ Kp, int kstride,
                                              const bf16* __restrict__ Vtg,
                                              const int* __restrict__ mask, int Mk,
                                              bf16* __restrict__ O) {
    __shared__ __attribute__((aligned(16))) bf16 Kt[64][88];      // [key][d]
    __shared__ __attribute__((aligned(16))) bf16 Vt[64][88];      // [d][key]
    __shared__ __attribute__((aligned(16))) bf16 Pt[4][16][88];   // [wave][q][key]
    __shared__ float madd[64];

    const int b = blockIdx.z, h = blockIdx.y;
    const int tid  = threadIdx.x;
    const int lane = tid & 63, wave = tid >> 6;
    const int lrow = lane & 15, quad = lane >> 4;
    const int q0 = blockIdx.x * 64 + wave * 16;

    const bf16* qp = Qp + ((size_t)(b * N_ + q0 + lrow)) * qstride + h * 64 + quad * 8;
    const bf16x8 bq0 = *(const bf16x8*)(qp);
    const bf16x8 bq1 = *(const bf16x8*)(qp + 32);

    f32x4 acc[4];
#pragma unroll
    for (int t = 0; t < 4; t++) acc[t] = (f32x4){0.f, 0.f, 0.f, 0.f};
    float mrun = -3e38f, lrun = 0.f;

    const int srow = tid >> 2;
    const int sseg = (tid & 3) * 16;

    const bf16* kbase = Kp + ((size_t)b * Mk + srow) * kstride + h * 64 + sseg;
    const bf16* vbase = Vtg + ((size_t)(b * 1024 + h * 64 + srow)) * Mk + sseg;

    for (int kc = 0; kc < Mk; kc += 64) {
        __syncthreads();
        const bf16* kp = kbase + (size_t)kc * kstride;
        bf16x8 k0 = *(const bf16x8*)kp;
        bf16x8 k1 = *(const bf16x8*)(kp + 8);
        *(bf16x8*)&Kt[srow][sseg]     = k0;
        *(bf16x8*)&Kt[srow][sseg + 8] = k1;
        const bf16* vp = vbase + kc;
        bf16x8 v0 = *(const bf16x8*)vp;
        bf16x8 v1 = *(const bf16x8*)(vp + 8);
        *(bf16x8*)&Vt[srow][sseg]     = v0;
        *(bf16x8*)&Vt[srow][sseg + 8] = v1;
        if (MASKED && tid < 64)
            madd[tid] = (mask[b * Mk + kc + tid] == 0) ? -1e30f : 0.f;
        __syncthreads();

        float sv[4][4];
#pragma unroll
        for (int t = 0; t < 4; t++) {
            f32x4 s = (f32x4){0.f, 0.f, 0.f, 0.f};
            bf16x8 ak0 = *(const bf16x8*)&Kt[t * 16 + lrow][quad * 8];
            s = mfma16(ak0, bq0, s);
            bf16x8 ak1 = *(const bf16x8*)&Kt[t * 16 + lrow][32 + quad * 8];
            s = mfma16(ak1, bq1, s);
#pragma unroll
            for (int r = 0; r < 4; r++) {
                float ma = MASKED ? madd[t * 16 + quad * 4 + r] : 0.f;
                sv[t][r] = s[r] * 0.125f + ma;
            }
        }

        float vmax = sv[0][0];
#pragma unroll
        for (int t = 0; t < 4; t++)
#pragma unroll
            for (int r = 0; r < 4; r++) vmax = fmaxf(vmax, sv[t][r]);
        vmax = fmaxf(vmax, __shfl_xor(vmax, 16));
        vmax = fmaxf(vmax, __shfl_xor(vmax, 32));
        const float mnew  = fmaxf(mrun, vmax);
        const float alpha = __expf(mrun - mnew);
        mrun = mnew;
        float rsum = 0.f;
#pragma unroll
        for (int t = 0; t < 4; t++) {
            bf16x4 p4;
#pragma unroll
            for (int r = 0; r < 4; r++) {
                float p = __expf(sv[t][r] - mnew);
                rsum += p;
                p4[r] = (bf16)p;
            }
            *(bf16x4*)&Pt[wave][lrow][t * 16 + quad * 4] = p4;
        }
        rsum += __shfl_xor(rsum, 16);
        rsum += __shfl_xor(rsum, 32);
        lrun = lrun * alpha + rsum;

        float alpha4[4];
#pragma unroll
    for (int r = 0; r < 4; r++) alpha4[r] = __shfl(alpha, quad * 4 + r);
#pragma unroll
        for (int t = 0; t < 4; t++)
#pragma unroll
            for (int r = 0; r < 4; r++) acc[t][r] *= alpha4[r];

        __syncthreads();
        const bf16x8 ap0 = *(const bf16x8*)&Pt[wave][lrow][quad * 8];
        const bf16x8 ap1 = *(const bf16x8*)&Pt[wave][lrow][32 + quad * 8];

#pragma unroll
        for (int t = 0; t < 4; t++) {
            bf16x8 bv0 = *(const bf16x8*)&Vt[t * 16 + lrow][quad * 8];
            acc[t] = mfma16(ap0, bv0, acc[t]);
            bf16x8 bv1 = *(const bf16x8*)&Vt[t * 16 + lrow][32 + quad * 8];
            acc[t] = mfma16(ap1, bv1, acc[t]);
        }
    }

    float linv = 1.f / lrun;
    float linv4[4];
#pragma unroll
    for (int r = 0; r < 4; r++) linv4[r] = __shfl(linv, quad * 4 + r);
#pragma unroll
    for (int r = 0; r < 4; r++) {
        const size_t grow = (size_t)(b * N_ + q0 + quad * 4 + r);
#pragma unroll
        for (int t = 0; t < 4; t++)
            O[grow * C_ + h * 64 + t * 16 + lrow] = (bf16)(acc[t][r] * linv4[r]);
    }
}

// ---------------------------------------------------------------------------
extern "C" void kernel_launch(void* const* d_in, const int* in_sizes, int n_in,
                              void* d_out, int out_size, void* d_ws, size_t ws_size,
                              hipStream_t stream) {
    const float* x     = (const float*)d_in[0];
    const float* cdino = (const float*)d_in[1];
    const float* ctext = (const float*)d_in[2];
    const int*   tmask = (const int*)d_in[3];
    const float* W_ada = (const float*)d_in[4];
    const float* b_ada = (const float*)d_in[5];
    const float* W_qkv = (const float*)d_in[6];
    const float* b_qkv = (const float*)d_in[7];
    const float* W_sa  = (const float*)d_in[8];
    const float* b_sa  = (const float*)d_in[9];
    const float* W_q   = (const float*)d_in[10];
    const float* b_q   = (const float*)d_in[11];
    const float* W_kv  = (const float*)d_in[12];
    const float* b_kv  = (const float*)d_in[13];
    const float* W_ca  = (const float*)d_in[14];
    const float* b_ca  = (const float*)d_in[15];
    const float* W_fc1 = (const float*)d_in[16];
    const float* b_fc1 = (const float*)d_in[17];
    const float* W_fc2 = (const float*)d_in[18];
    const float* b_fc2 = (const float*)d_in[19];
    float* out = (float*)d_out;

    char* ws = (char*)d_ws;
    size_t off = 0;
    auto alloc = [&](size_t bytes) -> char* {
        char* p = ws + off;
        off += (bytes + 255) & ~(size_t)255;
        return p;
    };
    float* ada  = (float*)alloc((size_t)8 * 6144 * 4);
    bf16* ctxb  = (bf16*)alloc((size_t)1024 * 1024 * 2);
    bf16* WqkvT = (bf16*)alloc((size_t)3072 * 1024 * 2);
    bf16* WsaT  = (bf16*)alloc((size_t)1024 * 1024 * 2);
    bf16* WqT   = (bf16*)alloc((size_t)1024 * 1024 * 2);
    bf16* WkvT  = (bf16*)alloc((size_t)2048 * 1024 * 2);
    bf16* WcaT  = (bf16*)alloc((size_t)1024 * 1024 * 2);
    bf16* Wfc1T = (bf16*)alloc((size_t)4096 * 1024 * 2);
    bf16* Wfc2T = (bf16*)alloc((size_t)1024 * 4096 * 2);
    float* xbuf = (float*)alloc((size_t)8192 * 1024 * 4);
    bf16* hbuf  = (bf16*)alloc((size_t)8192 * 1024 * 2);
    bf16* attnb = (bf16*)alloc((size_t)8192 * 1024 * 2);
    bf16* VtgSA = (bf16*)alloc((size_t)8192 * 1024 * 2);
    bf16* VtgCA = (bf16*)alloc((size_t)8192 * 128 * 2);
    bf16* pool  = (bf16*)alloc((size_t)8192 * 4096 * 2);
    if (off > ws_size) return;

    bf16* qkvb  = pool;
    bf16* qb    = pool;
    bf16* kvb   = pool + (size_t)8192 * 1024;
    bf16* gelub = pool;

    // --- weight prep ---
    transpose_k<<<dim3(3072 / 32, 1024 / 32), 256, 0, stream>>>(W_qkv, WqkvT, 1024, 3072);
    transpose_k<<<dim3(1024 / 32, 1024 / 32), 256, 0, stream>>>(W_sa,  WsaT,  1024, 1024);
    transpose_k<<<dim3(1024 / 32, 1024 / 32), 256, 0, stream>>>(W_q,   WqT,   1024, 1024);
    transpose_k<<<dim3(2048 / 32, 1024 / 32), 256, 0, stream>>>(W_kv,  WkvT,  1024, 2048);
    transpose_k<<<dim3(1024 / 32, 1024 / 32), 256, 0, stream>>>(W_ca,  WcaT,  1024, 1024);
    transpose_k<<<dim3(4096 / 32, 1024 / 32), 256, 0, stream>>>(W_fc1, Wfc1T, 1024, 4096);
    transpose_k<<<dim3(1024 / 32, 4096 / 32), 256, 0, stream>>>(W_fc2, Wfc2T, 4096, 1024);
    cvt_bf16_k<<<1024, 256, 0, stream>>>(ctext, ctxb, 262144);

    // --- ada ---
    ada_init_k<<<192, 256, 0, stream>>>(b_ada, ada);
    ada_k<<<dim3(24, 32), 256, 0, stream>>>(cdino, W_ada, ada);

    // --- self-attention ---
    ln_mod_k<<<8192, 256, 0, stream>>>(x, ada, 0, 1024, hbuf);
    gemm256_k<2><<<32 * 12, 512, 0, stream>>>(hbuf, WqkvT, b_qkv, qkvb, 3072, 1024, 12);
    vtrans_k<<<dim3(32, 32, 8), 256, 0, stream>>>(qkvb, 3072, 2048, 1024, VtgSA);
    attn_k<false><<<dim3(16, 16, 8), 256, 0, stream>>>(qkvb, 3072, qkvb + 1024, 3072, VtgSA,
                                                       nullptr, 1024, attnb);
    gemm_k<1, 2><<<8 * 64, 512, 0, stream>>>(attnb, WsaT, b_sa, x, xbuf, nullptr, 1024, 1024, 8);

    // --- cross-attention ---
    ln_mod_k<<<8192, 256, 0, stream>>>(xbuf, ada, 2048, 3072, hbuf);
    gemm_k<2, 2><<<8 * 64, 512, 0, stream>>>(hbuf, WqT, b_q, nullptr, nullptr, qb, 1024, 1024, 8);
    gemm_k<2, 2><<<16 * 8, 512, 0, stream>>>(ctxb, WkvT, b_kv, nullptr, nullptr, kvb, 2048, 1024, 16);
    vtrans_k<<<dim3(4, 32, 8), 256, 0, stream>>>(kvb, 2048, 1024, 128, VtgCA);
    attn_k<true><<<dim3(16, 16, 8), 256, 0, stream>>>(qb, 1024, kvb, 2048, VtgCA,
                                                      tmask, 128, attnb);
    gemm_k<1, 2><<<8 * 64, 512, 0, stream>>>(attnb, WcaT, b_ca, xbuf, xbuf, nullptr, 1024, 1024, 8);

    // --- MLP ---
    ln_mod_k<<<8192, 256, 0, stream>>>(xbuf, ada, 4096, 5120, hbuf);
    gemm256_k<3><<<32 * 16, 512, 0, stream>>>(hbuf, Wfc1T, b_fc1, gelub, 4096, 1024, 16);
    gemm_k<1, 2><<<8 * 64, 512, 0, stream>>>(gelub, Wfc2T, b_fc2, xbuf, out, nullptr, 1024, 4096, 8);
}